// Round 11
// baseline (568.231 us; speedup 1.0000x reference)
//
#include <hip/hip_runtime.h>

// Problem constants (fixed by the reference)
#define P 8
#define T 200
#define C 20
#define F 512
#define NQ 1024
#define MAXN 40                    // max samples per class we support (true ~10±4)
#define MMAX (T + MAXN)            // 240
#define PACK ((MMAX*(MMAX+1))/2)   // 28920 packed lower-tri floats
#define PACKA 29280                // row-padded-to-4 packed layout = rowS(MMAX) (LDS layout)
#define PACKT 40960                // tile-padded layout: row r padded to ((r>>6)+1)*64 cols (global W)
#define QL (NQ*C)                  // 20480 logits
#define NB 16                      // Cholesky panel width (R5/R6 NB=32 spilled; proven 16)
#define NTF 512                    // k_big block size (8 waves)
#define ETH 72                     // quarter-K E^T row stride in f16 (64 + 8 pad; lr*72%8==0 keeps b128 aligned)
#define XQS 72                     // sq/gram-path LDS row stride in f16 (64 + 8 pad)

// Fused-kernel block ranges: factor blocks FIRST (246 us serial critical path,
// 1 block/CU at 133 KB LDS); MFMA-sq / means / qnorm fill the ~96 idle CUs.
#define NBLK_FACTOR 160            // P*C
#define NBLK_SQ     128            // P x 4 t-tiles(64) x 4 q-tiles(256), MFMA
#define NBLK_MEANS  160            // P*C
#define NBLK_QNORM  128            // P*NQ/64 (8 waves x 8 rows)
#define NBLK_TOTAL  (NBLK_FACTOR + NBLK_SQ + NBLK_MEANS + NBLK_QNORM)

// Workspace layout (float offsets) — W region reinterpreted as two f16 planes
// (hi, lo) of PACKT each per (p,c): 2*PACKT*2B == PACKT*4B, byte-identical size.
enum : int {
  OFF_G    = 0,                       // P*T*T      = 320000
  OFF_SQ   = OFF_G   + P*T*T,         // P*T*NQ     = 1638400
  OFF_G1   = OFF_SQ  + P*T*NQ,        // P*T
  OFF_GG   = OFF_G1  + P*T,           // P
  OFF_GM   = OFF_GG  + P,             // P*T*C
  OFF_GMC  = OFF_GM  + P*T*C,         // P*C
  OFF_MM   = OFF_GMC + P*C,           // P*C
  OFF_GQ   = OFF_MM  + P*C,           // P*NQ
  OFF_QN   = OFF_GQ  + P*NQ,          // P*NQ
  OFF_MQ   = OFF_QN  + P*NQ,          // P*C*NQ
  OFF_W    = OFF_MQ  + P*C*NQ,        // P*C*PACKT floats = per (p,c): f16 hi[PACKT], lo[PACKT]
  OFF_QUAD = OFF_W   + P*C*PACKT,     // P*NQ*C
  OFF_CLSF = OFF_QUAD+ P*NQ*C,        // C*8 scalars
  OFF_INT  = OFF_CLSF+ C*8            // int region: counts[C], idx[C*MAXN]
};

typedef _Float16 f16x8 __attribute__((ext_vector_type(8)));
typedef _Float16 f16x4 __attribute__((ext_vector_type(4)));
typedef _Float16 f16x2 __attribute__((ext_vector_type(2)));
typedef float    f32x4 __attribute__((ext_vector_type(4)));

__device__ __forceinline__ int offr(int i){ return (i*(i+1))>>1; }

// 4-aligned row-padded packed layout (LDS): row i at rowS(i).
__device__ __forceinline__ int rowS(int i){
  int a = i >> 2, r = i & 3;
  return 8*a*(a+1) + 4*r*(a+1);
}

// tile-padded layout (global W planes): row r at rowT(r), length ((r>>6)+1)*64.
__device__ __forceinline__ int rowT(int r){
  const int R = r >> 6, s = r & 63;
  const int base = 4096 * ((R*(R+1)) >> 1);   // 0,4096,12288,24576
  return base + s*((R+1) << 6);
}

// flat packed index e -> row i (offr layout, used for tile triangles)
__device__ __forceinline__ int row_of(int e){
  int i = (int)((sqrtf(8.f*(float)e + 1.f) - 1.f) * 0.5f);
  while (offr(i+1) <= e) ++i;
  while (offr(i) > e) --i;
  return i;
}

// flat index e -> row i in rowS layout
__device__ __forceinline__ int row_ofS(int e){
  int i = (int)sqrtf(2.f*(float)e);
  if (i > MMAX-1) i = MMAX-1;
  while (i < MMAX-1 && rowS(i+1) <= e) ++i;
  while (i > 0 && rowS(i) > e) --i;
  return i;
}

// ---------------- setup: counts, per-class index lists, scalars ----------------
__global__ void k_setup(const int* lab, float* ws){
  int c = threadIdx.x;
  if (c >= C) return;
  int* wsI = (int*)(ws + OFF_INT);
  int n = 0;
  for (int t = 0; t < T; ++t){
    if (lab[t] == c){ if (n < MAXN) wsI[C + c*MAXN + n] = t; ++n; }
  }
  if (n > MAXN) n = MAXN;
  wsI[c] = n;
  float nf    = (float)n;
  float nsafe = fmaxf(nf, 1.0f);
  float dn    = fmaxf(nf - 1.0f, 1.0f);
  float lam   = nsafe / (nsafe + 1.0f);
  float sv    = (1.0f - lam) / (float)(T - 1);
  float av    = lam / dn;
  float* cf = ws + OFF_CLSF + c*8;
  cf[0] = nsafe; cf[1] = dn; cf[2] = lam; cf[3] = sv; cf[4] = av;
  cf[5] = sqrtf(sv); cf[6] = sqrtf(av); cf[7] = 0.0f;
}

// ---------------- G = X X^T per p via split-f16 MFMA + FUSED pstats_a (R11:
//   the ONLY fusion kept from R10's bundle — deletes the pstats_a launch).
//   Each block owns rows t0..t0+63 for ALL cols; after the G store drains at
//   __syncthreads (vmcnt(0) before s_barrier; lines never read before -> no
//   stale L1), the block computes g1 + Gm for its own rows. ----------------
__global__ __launch_bounds__(512) void k_gram(const float* __restrict__ X,
                                              float* __restrict__ ws){
  __shared__ _Float16 RH[64*XQS], RL[64*XQS];    // row tile (t0..t0+63)
  __shared__ _Float16 CH[256*XQS], CL[256*XQS];  // col tile (rows 0..255, zero-pad >= T)
  const int p = blockIdx.y, t0 = blockIdx.x*64;
  const int tid = threadIdx.x;
  const float* Xp = X + (size_t)p*T*F;
  const int wv = tid >> 6, ln = tid & 63;
  const int lr = ln & 15, lg = ln >> 4;
  const int wt = (wv & 1) * 32;          // wave row-base within tile
  const int wq = (wv >> 1) * 64;         // wave col-base within tile

  f32x4 acc[2][4] = {};

  for (int kb = 0; kb < F; kb += 64){
    for (int e = tid; e < 64*16; e += 512){
      const int r = e >> 4, l4 = (e & 15) * 4;
      float4 v = (t0 + r < T) ? *(const float4*)&Xp[(size_t)(t0+r)*F + kb + l4]
                              : make_float4(0.f,0.f,0.f,0.f);
      _Float16 h0=(_Float16)v.x, h1=(_Float16)v.y, h2=(_Float16)v.z, h3=(_Float16)v.w;
      f16x4 hv = {h0,h1,h2,h3};
      f16x4 lv = {(_Float16)(v.x-(float)h0),(_Float16)(v.y-(float)h1),
                  (_Float16)(v.z-(float)h2),(_Float16)(v.w-(float)h3)};
      *(f16x4*)&RH[r*XQS + l4] = hv;
      *(f16x4*)&RL[r*XQS + l4] = lv;
    }
    for (int e = tid; e < 256*16; e += 512){
      const int r = e >> 4, l4 = (e & 15) * 4;
      float4 v = (r < T) ? *(const float4*)&Xp[(size_t)r*F + kb + l4]
                         : make_float4(0.f,0.f,0.f,0.f);
      _Float16 h0=(_Float16)v.x, h1=(_Float16)v.y, h2=(_Float16)v.z, h3=(_Float16)v.w;
      f16x4 hv = {h0,h1,h2,h3};
      f16x4 lv = {(_Float16)(v.x-(float)h0),(_Float16)(v.y-(float)h1),
                  (_Float16)(v.z-(float)h2),(_Float16)(v.w-(float)h3)};
      *(f16x4*)&CH[r*XQS + l4] = hv;
      *(f16x4*)&CL[r*XQS + l4] = lv;
    }
    __syncthreads();
    #pragma unroll
    for (int s = 0; s < 2; ++s){
      const int ko = s*32 + 8*lg;
      f16x8 bh[4], bl[4];
      #pragma unroll
      for (int j = 0; j < 4; ++j){
        const int qr = wq + j*16 + lr;
        bh[j] = *(const f16x8*)&CH[qr*XQS + ko];
        bl[j] = *(const f16x8*)&CL[qr*XQS + ko];
      }
      #pragma unroll
      for (int i = 0; i < 2; ++i){
        const int tr = wt + i*16 + lr;
        f16x8 ah = *(const f16x8*)&RH[tr*XQS + ko];
        f16x8 al = *(const f16x8*)&RL[tr*XQS + ko];
        #pragma unroll
        for (int j = 0; j < 4; ++j){
          acc[i][j] = __builtin_amdgcn_mfma_f32_16x16x32_f16(ah, bh[j], acc[i][j], 0, 0, 0);
          acc[i][j] = __builtin_amdgcn_mfma_f32_16x16x32_f16(ah, bl[j], acc[i][j], 0, 0, 0);
          acc[i][j] = __builtin_amdgcn_mfma_f32_16x16x32_f16(al, bh[j], acc[i][j], 0, 0, 0);
        }
      }
    }
    __syncthreads();
  }
  // store: C/D layout col=lane&15, row=(lane>>4)*4+reg; guard t<T && col<T
  float* Gp = ws + OFF_G + (size_t)p*T*T;
  #pragma unroll
  for (int i = 0; i < 2; ++i){
    const int tb = t0 + wt + i*16 + lg*4;
    #pragma unroll
    for (int j = 0; j < 4; ++j){
      const int col = wq + j*16 + lr;
      if (col < T){
        #pragma unroll
        for (int r = 0; r < 4; ++r){
          const int t = tb + r;
          if (t < T) Gp[t*T + col] = acc[i][j][r];
        }
      }
    }
  }
  __syncthreads();   // drain G stores (vmcnt(0) before barrier) -> block-visible via L2

  // ---- fused pstats_a for this block's rows: g1 + Gm ----
  {
    const int* wsI = (const int*)(ws + OFF_INT);
    float* g1 = ws + OFF_G1 + p*T;
    float* Gm = ws + OFF_GM + (size_t)p*T*C;
    const int w = tid >> 6, lane = tid & 63;   // 8 waves x 8 rows
    for (int rr = 0; rr < 8; ++rr){
      const int t = t0 + w*8 + rr;
      if (t < T){
        float s = 0.f;
        for (int u2 = lane; u2 < T; u2 += 64) s += Gp[t*T + u2];
        for (int off = 32; off; off >>= 1) s += __shfl_down(s, off, 64);
        if (lane == 0) g1[t] = s * (1.0f/T);
        if (lane < C){
          int c = lane, nn = wsI[c];
          const int* idxc = wsI + C + c*MAXN;
          float sc = 0.f;
          for (int j = 0; j < nn; ++j) sc += Gp[t*T + idxc[j]];
          Gm[t*C + c] = sc / ws[OFF_CLSF + c*8];
        }
      }
    }
  }
}

// ---------------- per-p stats part B: gg, gmc, mm ----------------
__global__ __launch_bounds__(256) void k_pstats_b(float* ws){
  __shared__ float red[64];
  const int p = blockIdx.x, tid = threadIdx.x;
  const int* wsI = (const int*)(ws + OFF_INT);
  const float* g1 = ws + OFF_G1 + p*T;
  const float* Gm = ws + OFF_GM + (size_t)p*T*C;
  if (tid < 64){
    float s = 0.f;
    for (int t = tid; t < T; t += 64) s += g1[t];
    red[tid] = s;
  }
  __syncthreads();
  if (tid == 0){
    float s = 0.f;
    for (int k = 0; k < 64; ++k) s += red[k];
    ws[OFF_GG + p] = s * (1.0f/T);
  }
  if (tid < C){
    int c = tid, nn = wsI[c];
    const int* idxc = wsI + C + c*MAXN;
    float s = 0.f;
    for (int t = 0; t < T; ++t) s += Gm[t*C + c];
    ws[OFF_GMC + p*C + c] = s * (1.0f/T);
    float s2 = 0.f;
    for (int j = 0; j < nn; ++j) s2 += Gm[idxc[j]*C + c];
    ws[OFF_MM + p*C + c] = s2 / ws[OFF_CLSF + c*8];
  }
}

// ---------------- per-q stats: gq, mq (chunked, 128 blocks) ----------------
__global__ __launch_bounds__(256) void k_qstats(float* ws){
  __shared__ float red[4][64];
  const int p = blockIdx.y;
  const int qb = blockIdx.x*64;                   // gridDim.x = 16
  const int chunk = threadIdx.x >> 6, lane = threadIdx.x & 63;
  const int q = qb + lane;
  const int* wsI = (const int*)(ws + OFF_INT);
  const float* SQp = ws + OFF_SQ + (size_t)p*T*NQ;
  float s = 0.f;
  for (int t = chunk*50; t < chunk*50 + 50; ++t) s += SQp[t*NQ + q];
  red[chunk][lane] = s;
  __syncthreads();
  if (chunk == 0){
    float tot = red[0][lane] + red[1][lane] + red[2][lane] + red[3][lane];
    ws[OFF_GQ + p*NQ + q] = tot * (1.0f/T);
  }
  for (int c = chunk; c < C; c += 4){
    int nn = wsI[c];
    const int* idxc = wsI + C + c*MAXN;
    float sc = 0.f;
    for (int j = 0; j < nn; ++j) sc += SQp[idxc[j]*NQ + q];
    ws[OFF_MQ + ((size_t)(p*C + c))*NQ + q] = sc / ws[OFF_CLSF + c*8];
  }
}

// ============== FUSED BIG KERNEL: factor ∪ sq(MFMA) ∪ means ∪ qnorm ==============
// Factor path identical to the proven R9 version (246us, no spill, inversion
// early-break).

union __align__(16) BigShared {
  struct { float Lp[PACKA]; float Sb[16*228]; float Dv[NB][NB+1]; } f;        // 132800 B
  struct { _Float16 XHs[64*XQS], XLs[64*XQS], QHs[256*XQS], QLs[256*XQS]; } q; // 92160 B
};

__global__ __launch_bounds__(NTF) void k_big(const float* __restrict__ X,
                                             const float* __restrict__ Qf,
                                             float* __restrict__ ws,
                                             float* __restrict__ out){
  __shared__ BigShared u;
  const int bid = blockIdx.x;
  const int tid = threadIdx.x;
  const int* wsI = (const int*)(ws + OFF_INT);

  if (bid < NBLK_FACTOR){
    // ================= factor path (unchanged numerics) =================
    float* Lp = u.f.Lp;
    float* Sb = u.f.Sb;
    float (&Dv)[NB][NB+1] = u.f.Dv;
    const int blk = bid, p = blk / C, c = blk % C;
    const int n = wsI[c];
    const int m = T + n;
    const int* idxc = wsI + C + c*MAXN;
    const float* cf = ws + OFF_CLSF + c*8;
    const float sv = cf[3], av = cf[4], sqsa = cf[5]*cf[6];
    const float* Gp  = ws + OFF_G  + (size_t)p*T*T;
    const float* g1p = ws + OFF_G1 + p*T;
    const float  ggv = ws[OFF_GG + p];
    const float* Gmp = ws + OFF_GM + (size_t)p*T*C;
    const float gmcv = ws[OFF_GMC + p*C + c];
    const float mmv  = ws[OFF_MM  + p*C + c];

    // ---- build M in rowS layout; pads and rows >= m zeroed ----
    for (int e = tid; e < PACKA; e += NTF){
      int i = row_ofS(e);
      int j = e - rowS(i);
      float v = 0.f;
      if (i < m && j <= i){
        if (i < T){
          v = sv*(Gp[i*T + j] - g1p[i] - g1p[j] + ggv);
          if (j == i) v += 1.0f;
        } else {
          int ua = idxc[i - T];
          if (j < T){
            v = sqsa*(Gp[ua*T + j] - Gmp[j*C + c] - g1p[ua] + gmcv);
          } else {
            int ub = idxc[j - T];
            v = av*(Gp[ua*T + ub] - Gmp[ua*C + c] - Gmp[ub*C + c] + mmv);
            if (j == i) v += 1.0f;
          }
        }
      }
      Lp[e] = v;
    }
    __syncthreads();

    // ---- blocked right-looking Cholesky ----
    for (int k0 = 0; k0 < m; k0 += NB){
      // (a) diag 16x16 Cholesky + inverse inside wave 0 (no barriers)
      if (tid < 64){
        const int lane = tid;
        float a[NB];
        #pragma unroll
        for (int j = 0; j < NB; ++j){
          a[j] = 0.f;
          if (lane < NB && j <= lane) a[j] = Lp[rowS(k0+lane) + k0 + j];
        }
        #pragma unroll
        for (int k = 0; k < NB; ++k){
          float akk = __shfl(a[k], k, 64);
          float inv = rsqrtf(akk);
          a[k] *= inv;
          #pragma unroll
          for (int j = k+1; j < NB; ++j){
            float ljk = __shfl(a[k], j, 64);
            a[j] -= a[k] * ljk;
          }
        }
        float x[NB];
        #pragma unroll
        for (int i = 0; i < NB; ++i){
          float Lii = __shfl(a[i], i, 64);
          float sxx = 0.f;
          #pragma unroll
          for (int k2 = 0; k2 < i; ++k2){
            float Lik = __shfl(a[k2], i, 64);
            sxx += Lik * x[k2];
          }
          float tt = ((i == lane) ? 1.f : 0.f) - sxx;
          x[i] = tt / Lii;
        }
        if (lane < NB){
          #pragma unroll
          for (int i = 0; i < NB; ++i){
            Dv[i][lane] = (i >= lane) ? x[i] : 0.f;
            if (i >= lane) Lp[rowS(k0+i) + k0 + lane] = x[i];
          }
        }
      }
      __syncthreads();

      // (b) panel update: L[r][k0+j] = sum_{kk<=j} A[r][k0+kk] * Dinv[j][kk]
      for (int r = k0 + NB + tid; r < m; r += NTF){
        const int o = rowS(r) + k0;
        float4 A0 = *(const float4*)&Lp[o];
        float4 A1 = *(const float4*)&Lp[o+4];
        float4 A2 = *(const float4*)&Lp[o+8];
        float4 A3 = *(const float4*)&Lp[o+12];
        float ar[NB] = {A0.x,A0.y,A0.z,A0.w, A1.x,A1.y,A1.z,A1.w,
                        A2.x,A2.y,A2.z,A2.w, A3.x,A3.y,A3.z,A3.w};
        float sr[NB];
        #pragma unroll
        for (int j = 0; j < NB; ++j){
          float s = 0.f;
          #pragma unroll
          for (int kk = 0; kk <= j; ++kk) s += ar[kk] * Dv[j][kk];
          sr[j] = s;
        }
        *(float4*)&Lp[o]    = make_float4(sr[0], sr[1], sr[2], sr[3]);
        *(float4*)&Lp[o+4]  = make_float4(sr[4], sr[5], sr[6], sr[7]);
        *(float4*)&Lp[o+8]  = make_float4(sr[8], sr[9], sr[10], sr[11]);
        *(float4*)&Lp[o+12] = make_float4(sr[12], sr[13], sr[14], sr[15]);
      }
      __syncthreads();

      // (c) trailing SYRK directly from Lp (b128 reads; rows >= m are zero)
      const int rs = m - k0 - NB;
      if (rs > 0){
        const int base = k0 + NB;
        const int nt4 = (rs + 3) >> 2;
        const int ntile = (nt4*(nt4+1)) >> 1;
        for (int e2 = tid; e2 < ntile; e2 += NTF){
          const int ti = row_of(e2);
          const int tj = e2 - offr(ti);
          const int gi0 = base + 4*ti, gj0 = base + 4*tj;
          const float* pa0 = &Lp[rowS(gi0)   + k0];
          const float* pa1 = &Lp[rowS(gi0+1) + k0];
          const float* pa2 = &Lp[rowS(gi0+2) + k0];
          const float* pa3 = &Lp[rowS(gi0+3) + k0];
          const float* pb0 = &Lp[rowS(gj0)   + k0];
          const float* pb1 = &Lp[rowS(gj0+1) + k0];
          const float* pb2 = &Lp[rowS(gj0+2) + k0];
          const float* pb3 = &Lp[rowS(gj0+3) + k0];
          float acc[4][4] = {};
          #pragma unroll
          for (int kk = 0; kk < NB; kk += 4){
            float4 a0 = *(const float4*)(pa0+kk);
            float4 a1 = *(const float4*)(pa1+kk);
            float4 a2 = *(const float4*)(pa2+kk);
            float4 a3 = *(const float4*)(pa3+kk);
            float4 b0 = *(const float4*)(pb0+kk);
            float4 b1 = *(const float4*)(pb1+kk);
            float4 b2 = *(const float4*)(pb2+kk);
            float4 b3 = *(const float4*)(pb3+kk);
            acc[0][0] += a0.x*b0.x + a0.y*b0.y + a0.z*b0.z + a0.w*b0.w;
            acc[0][1] += a0.x*b1.x + a0.y*b1.y + a0.z*b1.z + a0.w*b1.w;
            acc[0][2] += a0.x*b2.x + a0.y*b2.y + a0.z*b2.z + a0.w*b2.w;
            acc[0][3] += a0.x*b3.x + a0.y*b3.y + a0.z*b3.z + a0.w*b3.w;
            acc[1][0] += a1.x*b0.x + a1.y*b0.y + a1.z*b0.z + a1.w*b0.w;
            acc[1][1] += a1.x*b1.x + a1.y*b1.y + a1.z*b1.z + a1.w*b1.w;
            acc[1][2] += a1.x*b2.x + a1.y*b2.y + a1.z*b2.z + a1.w*b2.w;
            acc[1][3] += a1.x*b3.x + a1.y*b3.y + a1.z*b3.z + a1.w*b3.w;
            acc[2][0] += a2.x*b0.x + a2.y*b0.y + a2.z*b0.z + a2.w*b0.w;
            acc[2][1] += a2.x*b1.x + a2.y*b1.y + a2.z*b1.z + a2.w*b1.w;
            acc[2][2] += a2.x*b2.x + a2.y*b2.y + a2.z*b2.z + a2.w*b2.w;
            acc[2][3] += a2.x*b3.x + a2.y*b3.y + a2.z*b3.z + a2.w*b3.w;
            acc[3][0] += a3.x*b0.x + a3.y*b0.y + a3.z*b0.z + a3.w*b0.w;
            acc[3][1] += a3.x*b1.x + a3.y*b1.y + a3.z*b1.z + a3.w*b1.w;
            acc[3][2] += a3.x*b2.x + a3.y*b2.y + a3.z*b2.z + a3.w*b2.w;
            acc[3][3] += a3.x*b3.x + a3.y*b3.y + a3.z*b3.z + a3.w*b3.w;
          }
          #pragma unroll
          for (int u2 = 0; u2 < 4; ++u2){
            const int gi = gi0 + u2;
            if (gi < m){
              const int og = rowS(gi);
              if (gj0 + 3 <= gi){
                float4 t = *(float4*)&Lp[og + gj0];
                t.x -= acc[u2][0]; t.y -= acc[u2][1]; t.z -= acc[u2][2]; t.w -= acc[u2][3];
                *(float4*)&Lp[og + gj0] = t;
              } else {
                #pragma unroll
                for (int v = 0; v < 4; ++v){
                  const int gj = gj0 + v;
                  if (gj <= gi) Lp[og + gj] -= acc[u2][v];
                }
              }
            }
          }
        }
      }
      __syncthreads();
    }

    // ---- full triangular inversion in place (ascending block-rows, all b128).
    //      Rounds with i0 >= m skipped — dead rows, never read; W store guards r < m. ----
    for (int I = 1; I < MMAX/NB; ++I){
      const int i0 = I*NB;
      if (i0 >= m) break;
      const int nct = i0 >> 2;
      const int rt = tid & 3, ct = tid >> 2;
      const int rt4 = rt*4;
      const int j0 = ct*4;
      int o0 = 0, o1 = 0, o2 = 0, o3 = 0;
      if (tid < 4*nct){
        const int r0 = i0 + rt4;
        o0 = rowS(r0); o1 = rowS(r0+1); o2 = rowS(r0+2); o3 = rowS(r0+3);
        float acc[4][4] = {};
        for (int k = j0; k < i0; k += 4){
          float4 l0 = *(const float4*)&Lp[o0+k];
          float4 l1 = *(const float4*)&Lp[o1+k];
          float4 l2 = *(const float4*)&Lp[o2+k];
          float4 l3 = *(const float4*)&Lp[o3+k];
          float4 x0 = *(const float4*)&Lp[rowS(k)  +j0];
          float4 x1 = *(const float4*)&Lp[rowS(k+1)+j0];
          float4 x2 = *(const float4*)&Lp[rowS(k+2)+j0];
          float4 x3 = *(const float4*)&Lp[rowS(k+3)+j0];
          acc[0][0] += l0.x*x0.x + l0.y*x1.x + l0.z*x2.x + l0.w*x3.x;
          acc[0][1] += l0.x*x0.y + l0.y*x1.y + l0.z*x2.y + l0.w*x3.y;
          acc[0][2] += l0.x*x0.z + l0.y*x1.z + l0.z*x2.z + l0.w*x3.z;
          acc[0][3] += l0.x*x0.w + l0.y*x1.w + l0.z*x2.w + l0.w*x3.w;
          acc[1][0] += l1.x*x0.x + l1.y*x1.x + l1.z*x2.x + l1.w*x3.x;
          acc[1][1] += l1.x*x0.y + l1.y*x1.y + l1.z*x2.y + l1.w*x3.y;
          acc[1][2] += l1.x*x0.z + l1.y*x1.z + l1.z*x2.z + l1.w*x3.z;
          acc[1][3] += l1.x*x0.w + l1.y*x1.w + l1.z*x2.w + l1.w*x3.w;
          acc[2][0] += l2.x*x0.x + l2.y*x1.x + l2.z*x2.x + l2.w*x3.x;
          acc[2][1] += l2.x*x0.y + l2.y*x1.y + l2.z*x2.y + l2.w*x3.y;
          acc[2][2] += l2.x*x0.z + l2.y*x1.z + l2.z*x2.z + l2.w*x3.z;
          acc[2][3] += l2.x*x0.w + l2.y*x1.w + l2.z*x2.w + l2.w*x3.w;
          acc[3][0] += l3.x*x0.x + l3.y*x1.x + l3.z*x2.x + l3.w*x3.x;
          acc[3][1] += l3.x*x0.y + l3.y*x1.y + l3.z*x2.y + l3.w*x3.y;
          acc[3][2] += l3.x*x0.z + l3.y*x1.z + l3.z*x2.z + l3.w*x3.z;
          acc[3][3] += l3.x*x0.w + l3.y*x1.w + l3.z*x2.w + l3.w*x3.w;
        }
        *(float4*)&Sb[(rt4  )*228 + j0] = make_float4(acc[0][0], acc[0][1], acc[0][2], acc[0][3]);
        *(float4*)&Sb[(rt4+1)*228 + j0] = make_float4(acc[1][0], acc[1][1], acc[1][2], acc[1][3]);
        *(float4*)&Sb[(rt4+2)*228 + j0] = make_float4(acc[2][0], acc[2][1], acc[2][2], acc[2][3]);
        *(float4*)&Sb[(rt4+3)*228 + j0] = make_float4(acc[3][0], acc[3][1], acc[3][2], acc[3][3]);
      }
      __syncthreads();
      if (tid < 4*nct){
        float acc[4][4] = {};
        for (int s = 0; s < rt4 + 4; ++s){
          const float d0 = Lp[o0 + i0 + s];   // pads beyond row give zero
          const float d1 = Lp[o1 + i0 + s];
          const float d2 = Lp[o2 + i0 + s];
          const float d3 = Lp[o3 + i0 + s];
          const float4 sv4 = *(const float4*)&Sb[s*228 + j0];
          acc[0][0] += d0*sv4.x; acc[0][1] += d0*sv4.y; acc[0][2] += d0*sv4.z; acc[0][3] += d0*sv4.w;
          acc[1][0] += d1*sv4.x; acc[1][1] += d1*sv4.y; acc[1][2] += d1*sv4.z; acc[1][3] += d1*sv4.w;
          acc[2][0] += d2*sv4.x; acc[2][1] += d2*sv4.y; acc[2][2] += d2*sv4.z; acc[2][3] += d2*sv4.w;
          acc[3][0] += d3*sv4.x; acc[3][1] += d3*sv4.y; acc[3][2] += d3*sv4.z; acc[3][3] += d3*sv4.w;
        }
        *(float4*)&Lp[o0 + j0] = make_float4(-acc[0][0], -acc[0][1], -acc[0][2], -acc[0][3]);
        *(float4*)&Lp[o1 + j0] = make_float4(-acc[1][0], -acc[1][1], -acc[1][2], -acc[1][3]);
        *(float4*)&Lp[o2 + j0] = make_float4(-acc[2][0], -acc[2][1], -acc[2][2], -acc[2][3]);
        *(float4*)&Lp[o3 + j0] = make_float4(-acc[3][0], -acc[3][1], -acc[3][2], -acc[3][3]);
      }
      __syncthreads();
    }

    // ---- store W = L^-1 as split-f16 planes (hi, lo) in tile-padded rowT layout ----
    _Float16* WH = (_Float16*)(ws + OFF_W) + (size_t)blk * (2*PACKT);
    _Float16* WL = WH + PACKT;
    // R=0: rows 0..63, len 64
    for (int e = tid; e < 64*64; e += NTF){
      int s = e >> 6, j = e & 63, r = s;
      float v = (r < m && j <= r) ? Lp[rowS(r) + j] : 0.f;
      _Float16 h = (_Float16)v;
      WH[e] = h; WL[e] = (_Float16)(v - (float)h);
    }
    // R=1: rows 64..127, len 128
    for (int e = tid; e < 64*128; e += NTF){
      int s = e >> 7, j = e & 127, r = 64 + s;
      float v = (r < m && j <= r) ? Lp[rowS(r) + j] : 0.f;
      _Float16 h = (_Float16)v;
      WH[4096 + e] = h; WL[4096 + e] = (_Float16)(v - (float)h);
    }
    // R=2: rows 128..191, len 192
    for (int e = tid; e < 64*192; e += NTF){
      int x = e >> 6;
      int s = (x*171) >> 9;            // x/3 for x < 512
      int j = e - s*192, r = 128 + s;
      float v = (r < m && j <= r) ? Lp[rowS(r) + j] : 0.f;
      _Float16 h = (_Float16)v;
      WH[12288 + e] = h; WL[12288 + e] = (_Float16)(v - (float)h);
    }
    // R=3: rows 192..255, len 256
    for (int e = tid; e < 64*256; e += NTF){
      int s = e >> 8, j = e & 255, r = 192 + s;
      float v = (r < m && j <= r) ? Lp[rowS(r) + j] : 0.f;
      _Float16 h = (_Float16)v;
      WH[24576 + e] = h; WL[24576 + e] = (_Float16)(v - (float)h);
    }

  } else if (bid < NBLK_FACTOR + NBLK_SQ){
    // ========== sq path: SQ = X Q^T via split-f16 MFMA (64t x 256q tile) ==========
    const int sb = bid - NBLK_FACTOR;
    const int p = sb >> 4, rem = sb & 15;
    const int t0 = (rem >> 2) * 64;        // t-tile base (rows >= T zero-padded)
    const int qb = (rem & 3) * 256;        // q-tile base
    _Float16* XH = u.q.XHs; _Float16* XL = u.q.XLs;
    _Float16* QH = u.q.QHs; _Float16* Qlo = u.q.QLs;
    const float* Xp = X  + (size_t)p*T*F;
    const float* Qp = Qf + (size_t)p*NQ*F;
    const int wv = tid >> 6, ln = tid & 63;
    const int lr = ln & 15, lg = ln >> 4;
    const int wt = (wv & 1) * 32;          // wave t-base within tile
    const int wq = (wv >> 1) * 64;         // wave q-base within tile

    f32x4 acc[2][4] = {};

    for (int kb = 0; kb < F; kb += 64){
      for (int e = tid; e < 64*16; e += NTF){
        const int r = e >> 4, l4 = (e & 15) * 4;
        float4 v = (t0 + r < T) ? *(const float4*)&Xp[(size_t)(t0+r)*F + kb + l4]
                                : make_float4(0.f,0.f,0.f,0.f);
        _Float16 h0=(_Float16)v.x, h1=(_Float16)v.y, h2=(_Float16)v.z, h3=(_Float16)v.w;
        f16x4 hv = {h0,h1,h2,h3};
        f16x4 lv = {(_Float16)(v.x-(float)h0),(_Float16)(v.y-(float)h1),
                    (_Float16)(v.z-(float)h2),(_Float16)(v.w-(float)h3)};
        *(f16x4*)&XH[r*XQS + l4] = hv;
        *(f16x4*)&XL[r*XQS + l4] = lv;
      }
      for (int e = tid; e < 256*16; e += NTF){
        const int r = e >> 4, l4 = (e & 15) * 4;
        float4 v = *(const float4*)&Qp[(size_t)(qb+r)*F + kb + l4];
        _Float16 h0=(_Float16)v.x, h1=(_Float16)v.y, h2=(_Float16)v.z, h3=(_Float16)v.w;
        f16x4 hv = {h0,h1,h2,h3};
        f16x4 lv = {(_Float16)(v.x-(float)h0),(_Float16)(v.y-(float)h1),
                    (_Float16)(v.z-(float)h2),(_Float16)(v.w-(float)h3)};
        *(f16x4*)&QH[r*XQS + l4] = hv;
        *(f16x4*)&Qlo[r*XQS + l4] = lv;
      }
      __syncthreads();
      #pragma unroll
      for (int s = 0; s < 2; ++s){
        const int ko = s*32 + 8*lg;
        f16x8 bh[4], bl[4];
        #pragma unroll
        for (int j = 0; j < 4; ++j){
          const int qr = wq + j*16 + lr;
          bh[j] = *(const f16x8*)&QH[qr*XQS + ko];
          bl[j] = *(const f16x8*)&Qlo[qr*XQS + ko];
        }
        #pragma unroll
        for (int i = 0; i < 2; ++i){
          const int tr = wt + i*16 + lr;
          f16x8 ah = *(const f16x8*)&XH[tr*XQS + ko];
          f16x8 al = *(const f16x8*)&XL[tr*XQS + ko];
          #pragma unroll
          for (int j = 0; j < 4; ++j){
            acc[i][j] = __builtin_amdgcn_mfma_f32_16x16x32_f16(ah, bh[j], acc[i][j], 0, 0, 0);
            acc[i][j] = __builtin_amdgcn_mfma_f32_16x16x32_f16(ah, bl[j], acc[i][j], 0, 0, 0);
            acc[i][j] = __builtin_amdgcn_mfma_f32_16x16x32_f16(al, bh[j], acc[i][j], 0, 0, 0);
          }
        }
      }
      __syncthreads();
    }
    // store: C/D layout col=lane&15, row=(lane>>4)*4+reg
    float* SQp = ws + OFF_SQ + (size_t)p*T*NQ;
    #pragma unroll
    for (int i = 0; i < 2; ++i){
      const int tb = t0 + wt + i*16 + lg*4;
      #pragma unroll
      for (int j = 0; j < 4; ++j){
        const int qc = qb + wq + j*16 + lr;
        #pragma unroll
        for (int r = 0; r < 4; ++r){
          const int t = tb + r;
          if (t < T) SQp[t*NQ + qc] = acc[i][j][r];
        }
      }
    }

  } else if (bid < NBLK_FACTOR + NBLK_SQ + NBLK_MEANS){
    // ================= means path -> output part 2 =================
    const int mb = bid - NBLK_FACTOR - NBLK_SQ;
    const int p = mb / C, c = mb % C;
    const int n = wsI[c];
    const int* idxc = wsI + C + c*MAXN;
    const float nf = ws[OFF_CLSF + c*8];
    const float* Xp = X + (size_t)p*T*F;
    float* o = out + QL + (size_t)(p*C + c)*F;
    for (int f = tid; f < F; f += NTF){
      float s = 0.f;
      for (int j = 0; j < n; ++j) s += Xp[idxc[j]*F + f];
      o[f] = s / nf;
    }

  } else {
    // ================= qnorm path: ||q||^2, 8 rows per wave =================
    const int qb2 = bid - NBLK_FACTOR - NBLK_SQ - NBLK_MEANS;   // [0,128)
    const int w = tid >> 6, lane = tid & 63;
    const int row0 = qb2*64 + w*8;
    for (int i = 0; i < 8; ++i){
      const int row = row0 + i;
      const float4* q4p = (const float4*)(Qf + (size_t)row*F);
      float4 v0 = q4p[lane];
      float4 v1 = q4p[lane + 64];
      float s = v0.x*v0.x + v0.y*v0.y + v0.z*v0.z + v0.w*v0.w
              + v1.x*v1.x + v1.y*v1.y + v1.z*v1.z + v1.w*v1.w;
      for (int off = 32; off; off >>= 1) s += __shfl_down(s, off, 64);
      if (lane == 0) ws[OFF_QN + row] = s;
    }
  }
}

// ---------------- apply: z = W*e via split-f16 MFMA, K-QUARTERED E^T staging
//   (proven R7/R9 version, byte-identical). ----------------
__global__ __launch_bounds__(256) void k_apply(float* ws){
  __shared__ __align__(16) _Float16 EtH[64*ETH];  // 9216 B  [q][k-quarter] hi plane
  __shared__ __align__(16) _Float16 EtL[64*ETH];  // 9216 B  [q][k-quarter] lo plane
  __shared__ float Ef[32*65];                     // 8320 B  f32 build chunk [j][q], stride 65
  __shared__ float Part[4][64];                   // 1024 B  per-wave ||z||^2 partials
  const int p = blockIdx.z, c = blockIdx.y, q0 = blockIdx.x*64;
  const int tid = threadIdx.x;
  const int* wsI = (const int*)(ws + OFF_INT);
  const int n = wsI[c], m = T + n;
  const int* idxc = wsI + C + c*MAXN;
  const float* cf = ws + OFF_CLSF + c*8;
  const float sqs = cf[5], sqa = cf[6];
  const float gmcv = ws[OFF_GMC + p*C + c];
  const float mmv  = ws[OFF_MM  + p*C + c];
  const float* Gmp = ws + OFF_GM + (size_t)p*T*C;
  const float* SQp = ws + OFF_SQ + (size_t)p*T*NQ;
  const float* gqp = ws + OFF_GQ + p*NQ + q0;
  const float* qnp = ws + OFF_QN + p*NQ + q0;
  const float* mqp = ws + OFF_MQ + ((size_t)(p*C + c))*NQ + q0;

  const int wv = tid >> 6, ln = tid & 63;
  const int lr = ln & 15;          // A row / B col (q) within tile
  const int lg = ln >> 4;          // k-group
  const _Float16* WH = (const _Float16*)(ws + OFF_W) + (size_t)(p*C + c)*(2*PACKT);
  const _Float16* WL = WH + PACKT;
  int aoff[4];
  #pragma unroll
  for (int i = 0; i < 4; ++i){
    const int t = wv + 4*i;
    aoff[i] = rowT(16*t + lr) + 8*lg;
  }

  f32x4 acc[4][4] = {};            // [rowtile][qtile], 4 f32 each; persists across quarters

  for (int h = 0; h < 4; ++h){
    // ---- build quarter h: E rows [64h, 64h+64) in two 32-row chunks ----
    for (int ch = 0; ch < 2; ++ch){
      const int jbl = ch*32;                // local row base within quarter
      const int jb = h*64 + jbl;            // absolute E row base
      for (int e = tid; e < 32*64; e += 256){
        const int jl = e >> 6, q = e & 63;
        const int j = jb + jl;
        float v = 0.f;
        if (j < T){
          v = sqs*(Gmp[j*C + c] - SQp[j*NQ + q0 + q] - gmcv + gqp[q]);
        } else if (j < m){
          const int u2 = idxc[j - T];
          v = sqa*(Gmp[u2*C + c] - SQp[u2*NQ + q0 + q] - mmv + mqp[q]);
        }
        Ef[jl*65 + q] = v;
      }
      __syncthreads();                      // also fences prior quarter's Et reads
      for (int e = tid; e < 16*64; e += 256){
        const int jp = e & 15, q = e >> 4;
        const int jl = 2*jp;
        const float v0 = Ef[jl*65 + q];
        const float v1 = Ef[(jl+1)*65 + q];
        const _Float16 h0 = (_Float16)v0, h1 = (_Float16)v1;
        f16x2 hv; hv[0] = h0; hv[1] = h1;
        f16x2 lv; lv[0] = (_Float16)(v0 - (float)h0); lv[1] = (_Float16)(v1 - (float)h1);
        *(f16x2*)&EtH[q*ETH + jbl + jl] = hv;
        *(f16x2*)&EtL[q*ETH + jbl + jl] = lv;
      }
      __syncthreads();
    }

    // ---- MFMA over this quarter: s in {2h, 2h+1} ----
    #pragma unroll
    for (int sl = 0; sl < 2; ++sl){
      const int s = 2*h + sl;
      if (2*s > wv + 12) continue;          // no active row-tile for this wave
      const int k0 = 32*s;
      const int bo = lr*ETH + (k0 - 64*h) + 8*lg;
      f16x8 bh[4], bl[4];
      #pragma unroll
      for (int ct2 = 0; ct2 < 4; ++ct2){
        bh[ct2] = *(const f16x8*)&EtH[ct2*16*ETH + bo];
        bl[ct2] = *(const f16x8*)&EtL[ct2*16*ETH + bo];
      }
      #pragma unroll
      for (int i = 0; i < 4; ++i){
        const int t = wv + 4*i;
        if (2*s <= t){                      // triangular K-extent: tile t needs k < 16(t+1)
          f16x8 ah = *(const f16x8*)(WH + aoff[i] + k0);
          f16x8 al = *(const f16x8*)(WL + aoff[i] + k0);
          #pragma unroll
          for (int ct2 = 0; ct2 < 4; ++ct2){
            acc[i][ct2] = __builtin_amdgcn_mfma_f32_16x16x32_f16(ah, bh[ct2], acc[i][ct2], 0, 0, 0);
            acc[i][ct2] = __builtin_amdgcn_mfma_f32_16x16x32_f16(ah, bl[ct2], acc[i][ct2], 0, 0, 0);
            acc[i][ct2] = __builtin_amdgcn_mfma_f32_16x16x32_f16(al, bh[ct2], acc[i][ct2], 0, 0, 0);
          }
        }
      }
    }
  }

  // ---- ||z||^2 per query: per-lane squares, butterfly over k-groups, LDS combine ----
  #pragma unroll
  for (int ct2 = 0; ct2 < 4; ++ct2){
    float sthread = 0.f;
    #pragma unroll
    for (int i = 0; i < 4; ++i){
      const f32x4 a4 = acc[i][ct2];
      sthread += a4[0]*a4[0] + a4[1]*a4[1] + a4[2]*a4[2] + a4[3]*a4[3];
    }
    sthread += __shfl_xor(sthread, 16, 64);
    sthread += __shfl_xor(sthread, 32, 64);
    if (ln < 16) Part[wv][ct2*16 + ln] = sthread;
  }
  __syncthreads();
  if (tid < 64){
    const float tt = Part[0][tid] + Part[1][tid] + Part[2][tid] + Part[3][tid];
    const float quad = mmv - 2.f*mqp[tid] + qnp[tid] - tt;
    ws[OFF_QUAD + ((size_t)p*NQ + q0 + tid)*C + c] = quad;
  }
}

// ---------------- logits: mean over p ----------------
__global__ void k_logits(const float* ws, float* out){
  int lin = blockIdx.x*256 + threadIdx.x;
  if (lin < QL){
    float s = 0.f;
    for (int p = 0; p < P; ++p) s += ws[OFF_QUAD + (size_t)p*NQ*C + lin];
    out[lin] = -s * (1.0f/P);
  }
}

extern "C" void kernel_launch(void* const* d_in, const int* in_sizes, int n_in,
                              void* d_out, int out_size, void* d_ws, size_t ws_size,
                              hipStream_t stream){
  const float* X   = (const float*)d_in[0];
  const int*   lab = (const int*)d_in[1];
  const float* Qf  = (const float*)d_in[2];
  float* out = (float*)d_out;
  float* ws  = (float*)d_ws;

  k_setup   <<<1, 64, 0, stream>>>(lab, ws);
  k_gram    <<<dim3(4,P), 512, 0, stream>>>(X, ws);
  k_pstats_b<<<P, 256, 0, stream>>>(ws);
  k_big     <<<NBLK_TOTAL, NTF, 0, stream>>>(X, Qf, ws, out);
  k_qstats  <<<dim3(16,P), 256, 0, stream>>>(ws);
  k_apply   <<<dim3(16,C,P), 256, 0, stream>>>(ws);
  k_logits  <<<QL/256, 256, 0, stream>>>(ws, out);
}

// Round 12
// 538.296 us; speedup vs baseline: 1.0556x; 1.0556x over previous
//
#include <hip/hip_runtime.h>

// Problem constants (fixed by the reference)
#define P 8
#define T 200
#define C 20
#define F 512
#define NQ 1024
#define MAXN 40                    // max samples per class we support (true ~10±4)
#define MMAX (T + MAXN)            // 240
#define PACK ((MMAX*(MMAX+1))/2)   // 28920 packed lower-tri floats
#define PACKA 29280                // row-padded-to-4 packed layout = rowS(MMAX) (LDS layout)
#define PACKT 40960                // tile-padded layout: row r padded to ((r>>6)+1)*64 cols (global W)
#define QL (NQ*C)                  // 20480 logits
#define NB 16                      // Cholesky panel width (R5/R6 NB=32 spilled; proven 16)
#define NTF 512                    // k_big block size (8 waves)
#define ETH 72                     // quarter-K E^T row stride in f16 (64 + 8 pad; lr*72%8==0 keeps b128 aligned)
#define XQS 72                     // sq/gram-path LDS row stride in f16 (64 + 8 pad)

// Fused-kernel block ranges: factor blocks FIRST (246 us serial critical path,
// 1 block/CU at 133 KB LDS); MFMA-sq / means / qnorm fill the ~96 idle CUs.
#define NBLK_FACTOR 160            // P*C
#define NBLK_SQ     128            // P x 4 t-tiles(64) x 4 q-tiles(256), MFMA
#define NBLK_MEANS  160            // P*C
#define NBLK_QNORM  128            // P*NQ/64 (8 waves x 8 rows)
#define NBLK_TOTAL  (NBLK_FACTOR + NBLK_SQ + NBLK_MEANS + NBLK_QNORM)

// Workspace layout (float offsets) — W region reinterpreted as two f16 planes
// (hi, lo) of PACKT each per (p,c): 2*PACKT*2B == PACKT*4B, byte-identical size.
enum : int {
  OFF_G    = 0,                       // P*T*T      = 320000
  OFF_SQ   = OFF_G   + P*T*T,         // P*T*NQ     = 1638400
  OFF_G1   = OFF_SQ  + P*T*NQ,        // P*T
  OFF_GG   = OFF_G1  + P*T,           // P
  OFF_GM   = OFF_GG  + P,             // P*T*C
  OFF_GMC  = OFF_GM  + P*T*C,         // P*C
  OFF_MM   = OFF_GMC + P*C,           // P*C
  OFF_GQ   = OFF_MM  + P*C,           // P*NQ
  OFF_QN   = OFF_GQ  + P*NQ,          // P*NQ
  OFF_MQ   = OFF_QN  + P*NQ,          // P*C*NQ
  OFF_W    = OFF_MQ  + P*C*NQ,        // P*C*PACKT floats = per (p,c): f16 hi[PACKT], lo[PACKT]
  OFF_QUAD = OFF_W   + P*C*PACKT,     // P*NQ*C
  OFF_CLSF = OFF_QUAD+ P*NQ*C,        // C*8 scalars
  OFF_INT  = OFF_CLSF+ C*8            // int region: counts[C], idx[C*MAXN]
};

typedef _Float16 f16x8 __attribute__((ext_vector_type(8)));
typedef _Float16 f16x4 __attribute__((ext_vector_type(4)));
typedef _Float16 f16x2 __attribute__((ext_vector_type(2)));
typedef float    f32x4 __attribute__((ext_vector_type(4)));

__device__ __forceinline__ int offr(int i){ return (i*(i+1))>>1; }

// 4-aligned row-padded packed layout (LDS): row i at rowS(i).
__device__ __forceinline__ int rowS(int i){
  int a = i >> 2, r = i & 3;
  return 8*a*(a+1) + 4*r*(a+1);
}

// tile-padded layout (global W planes): row r at rowT(r), length ((r>>6)+1)*64.
__device__ __forceinline__ int rowT(int r){
  const int R = r >> 6, s = r & 63;
  const int base = 4096 * ((R*(R+1)) >> 1);   // 0,4096,12288,24576
  return base + s*((R+1) << 6);
}

// flat packed index e -> row i (offr layout, used for tile triangles)
__device__ __forceinline__ int row_of(int e){
  int i = (int)((sqrtf(8.f*(float)e + 1.f) - 1.f) * 0.5f);
  while (offr(i+1) <= e) ++i;
  while (offr(i) > e) --i;
  return i;
}

// flat index e -> row i in rowS layout
__device__ __forceinline__ int row_ofS(int e){
  int i = (int)sqrtf(2.f*(float)e);
  if (i > MMAX-1) i = MMAX-1;
  while (i < MMAX-1 && rowS(i+1) <= e) ++i;
  while (i > 0 && rowS(i) > e) --i;
  return i;
}

// ---------------- setup: counts, per-class index lists, scalars ----------------
__global__ void k_setup(const int* lab, float* ws){
  int c = threadIdx.x;
  if (c >= C) return;
  int* wsI = (int*)(ws + OFF_INT);
  int n = 0;
  for (int t = 0; t < T; ++t){
    if (lab[t] == c){ if (n < MAXN) wsI[C + c*MAXN + n] = t; ++n; }
  }
  if (n > MAXN) n = MAXN;
  wsI[c] = n;
  float nf    = (float)n;
  float nsafe = fmaxf(nf, 1.0f);
  float dn    = fmaxf(nf - 1.0f, 1.0f);
  float lam   = nsafe / (nsafe + 1.0f);
  float sv    = (1.0f - lam) / (float)(T - 1);
  float av    = lam / dn;
  float* cf = ws + OFF_CLSF + c*8;
  cf[0] = nsafe; cf[1] = dn; cf[2] = lam; cf[3] = sv; cf[4] = av;
  cf[5] = sqrtf(sv); cf[6] = sqrtf(av); cf[7] = 0.0f;
}

// ---------------- G = X X^T per p via split-f16 MFMA.
//   64 t-rows x 256 t-cols per block, K=512; 8p x 4 row-tiles = 32 blocks.
//   G = (Xh+Xl)(Xh+Xl)^T ~= Xh*Xh + Xh*Xl + Xl*Xh, f32 accumulate. ----------------
__global__ __launch_bounds__(512) void k_gram(const float* __restrict__ X,
                                              float* __restrict__ ws){
  __shared__ _Float16 RH[64*XQS], RL[64*XQS];    // row tile (t0..t0+63)
  __shared__ _Float16 CH[256*XQS], CL[256*XQS];  // col tile (rows 0..255, zero-pad >= T)
  const int p = blockIdx.y, t0 = blockIdx.x*64;
  const int tid = threadIdx.x;
  const float* Xp = X + (size_t)p*T*F;
  const int wv = tid >> 6, ln = tid & 63;
  const int lr = ln & 15, lg = ln >> 4;
  const int wt = (wv & 1) * 32;          // wave row-base within tile
  const int wq = (wv >> 1) * 64;         // wave col-base within tile

  f32x4 acc[2][4] = {};

  for (int kb = 0; kb < F; kb += 64){
    // stage row chunk: 64 rows x 64 k
    for (int e = tid; e < 64*16; e += 512){
      const int r = e >> 4, l4 = (e & 15) * 4;
      float4 v = (t0 + r < T) ? *(const float4*)&Xp[(size_t)(t0+r)*F + kb + l4]
                              : make_float4(0.f,0.f,0.f,0.f);
      _Float16 h0=(_Float16)v.x, h1=(_Float16)v.y, h2=(_Float16)v.z, h3=(_Float16)v.w;
      f16x4 hv = {h0,h1,h2,h3};
      f16x4 lv = {(_Float16)(v.x-(float)h0),(_Float16)(v.y-(float)h1),
                  (_Float16)(v.z-(float)h2),(_Float16)(v.w-(float)h3)};
      *(f16x4*)&RH[r*XQS + l4] = hv;
      *(f16x4*)&RL[r*XQS + l4] = lv;
    }
    // stage col chunk: 256 rows x 64 k (zero-pad rows >= T)
    for (int e = tid; e < 256*16; e += 512){
      const int r = e >> 4, l4 = (e & 15) * 4;
      float4 v = (r < T) ? *(const float4*)&Xp[(size_t)r*F + kb + l4]
                         : make_float4(0.f,0.f,0.f,0.f);
      _Float16 h0=(_Float16)v.x, h1=(_Float16)v.y, h2=(_Float16)v.z, h3=(_Float16)v.w;
      f16x4 hv = {h0,h1,h2,h3};
      f16x4 lv = {(_Float16)(v.x-(float)h0),(_Float16)(v.y-(float)h1),
                  (_Float16)(v.z-(float)h2),(_Float16)(v.w-(float)h3)};
      *(f16x4*)&CH[r*XQS + l4] = hv;
      *(f16x4*)&CL[r*XQS + l4] = lv;
    }
    __syncthreads();
    #pragma unroll
    for (int s = 0; s < 2; ++s){
      const int ko = s*32 + 8*lg;
      f16x8 bh[4], bl[4];
      #pragma unroll
      for (int j = 0; j < 4; ++j){
        const int qr = wq + j*16 + lr;
        bh[j] = *(const f16x8*)&CH[qr*XQS + ko];
        bl[j] = *(const f16x8*)&CL[qr*XQS + ko];
      }
      #pragma unroll
      for (int i = 0; i < 2; ++i){
        const int tr = wt + i*16 + lr;
        f16x8 ah = *(const f16x8*)&RH[tr*XQS + ko];
        f16x8 al = *(const f16x8*)&RL[tr*XQS + ko];
        #pragma unroll
        for (int j = 0; j < 4; ++j){
          acc[i][j] = __builtin_amdgcn_mfma_f32_16x16x32_f16(ah, bh[j], acc[i][j], 0, 0, 0);
          acc[i][j] = __builtin_amdgcn_mfma_f32_16x16x32_f16(ah, bl[j], acc[i][j], 0, 0, 0);
          acc[i][j] = __builtin_amdgcn_mfma_f32_16x16x32_f16(al, bh[j], acc[i][j], 0, 0, 0);
        }
      }
    }
    __syncthreads();
  }
  // store: C/D layout col=lane&15, row=(lane>>4)*4+reg; guard t<T && col<T
  float* Gp = ws + OFF_G + (size_t)p*T*T;
  #pragma unroll
  for (int i = 0; i < 2; ++i){
    const int tb = t0 + wt + i*16 + lg*4;
    #pragma unroll
    for (int j = 0; j < 4; ++j){
      const int col = wq + j*16 + lr;
      if (col < T){
        #pragma unroll
        for (int r = 0; r < 4; ++r){
          const int t = tb + r;
          if (t < T) Gp[t*T + col] = acc[i][j][r];
        }
      }
    }
  }
}

// ---------------- per-p stats part A: g1 rows + Gm (coalesced, 200 blocks) ----------------
__global__ __launch_bounds__(256) void k_pstats_a(float* ws){
  const int p = blockIdx.y, bx = blockIdx.x;      // bx in [0,25)
  const int w = threadIdx.x >> 6, lane = threadIdx.x & 63;
  const int* wsI = (const int*)(ws + OFF_INT);
  const float* Gp = ws + OFF_G + (size_t)p*T*T;
  float* g1 = ws + OFF_G1 + p*T;
  float* Gm = ws + OFF_GM + (size_t)p*T*C;
  for (int rr = 0; rr < 2; ++rr){
    const int t = bx*8 + w*2 + rr;                // 25*8 = 200 rows exactly
    float s = 0.f;
    for (int u = lane; u < T; u += 64) s += Gp[t*T + u];
    for (int off = 32; off; off >>= 1) s += __shfl_down(s, off, 64);
    if (lane == 0) g1[t] = s * (1.0f/T);
    if (lane < C){
      int c = lane, nn = wsI[c];
      const int* idxc = wsI + C + c*MAXN;
      float sc = 0.f;
      for (int j = 0; j < nn; ++j) sc += Gp[t*T + idxc[j]];
      Gm[t*C + c] = sc / ws[OFF_CLSF + c*8];
    }
  }
}

// ---------------- per-p stats part B: gg, gmc, mm ----------------
__global__ __launch_bounds__(256) void k_pstats_b(float* ws){
  __shared__ float red[64];
  const int p = blockIdx.x, tid = threadIdx.x;
  const int* wsI = (const int*)(ws + OFF_INT);
  const float* g1 = ws + OFF_G1 + p*T;
  const float* Gm = ws + OFF_GM + (size_t)p*T*C;
  if (tid < 64){
    float s = 0.f;
    for (int t = tid; t < T; t += 64) s += g1[t];
    red[tid] = s;
  }
  __syncthreads();
  if (tid == 0){
    float s = 0.f;
    for (int k = 0; k < 64; ++k) s += red[k];
    ws[OFF_GG + p] = s * (1.0f/T);
  }
  if (tid < C){
    int c = tid, nn = wsI[c];
    const int* idxc = wsI + C + c*MAXN;
    float s = 0.f;
    for (int t = 0; t < T; ++t) s += Gm[t*C + c];
    ws[OFF_GMC + p*C + c] = s * (1.0f/T);
    float s2 = 0.f;
    for (int j = 0; j < nn; ++j) s2 += Gm[idxc[j]*C + c];
    ws[OFF_MM + p*C + c] = s2 / ws[OFF_CLSF + c*8];
  }
}

// ---------------- per-q stats: gq, mq (chunked, 128 blocks) ----------------
__global__ __launch_bounds__(256) void k_qstats(float* ws){
  __shared__ float red[4][64];
  const int p = blockIdx.y;
  const int qb = blockIdx.x*64;                   // gridDim.x = 16
  const int chunk = threadIdx.x >> 6, lane = threadIdx.x & 63;
  const int q = qb + lane;
  const int* wsI = (const int*)(ws + OFF_INT);
  const float* SQp = ws + OFF_SQ + (size_t)p*T*NQ;
  float s = 0.f;
  for (int t = chunk*50; t < chunk*50 + 50; ++t) s += SQp[t*NQ + q];
  red[chunk][lane] = s;
  __syncthreads();
  if (chunk == 0){
    float tot = red[0][lane] + red[1][lane] + red[2][lane] + red[3][lane];
    ws[OFF_GQ + p*NQ + q] = tot * (1.0f/T);
  }
  for (int c = chunk; c < C; c += 4){
    int nn = wsI[c];
    const int* idxc = wsI + C + c*MAXN;
    float sc = 0.f;
    for (int j = 0; j < nn; ++j) sc += SQp[idxc[j]*NQ + q];
    ws[OFF_MQ + ((size_t)(p*C + c))*NQ + q] = sc / ws[OFF_CLSF + c*8];
  }
}

// ============== FUSED BIG KERNEL: factor ∪ sq(MFMA) ∪ means ∪ qnorm ==============
// Factor path identical to the proven R4/R7 version (no spill) + the R8
// inversion early-break (i0 >= m rows are dead; W store guards r < m).

union __align__(16) BigShared {
  struct { float Lp[PACKA]; float Sb[16*228]; float Dv[NB][NB+1]; } f;        // 132800 B
  struct { _Float16 XHs[64*XQS], XLs[64*XQS], QHs[256*XQS], QLs[256*XQS]; } q; // 92160 B
};

__global__ __launch_bounds__(NTF) void k_big(const float* __restrict__ X,
                                             const float* __restrict__ Qf,
                                             float* __restrict__ ws,
                                             float* __restrict__ out){
  __shared__ BigShared u;
  const int bid = blockIdx.x;
  const int tid = threadIdx.x;
  const int* wsI = (const int*)(ws + OFF_INT);

  if (bid < NBLK_FACTOR){
    // ================= factor path (unchanged numerics) =================
    float* Lp = u.f.Lp;
    float* Sb = u.f.Sb;
    float (&Dv)[NB][NB+1] = u.f.Dv;
    const int blk = bid, p = blk / C, c = blk % C;
    const int n = wsI[c];
    const int m = T + n;
    const int* idxc = wsI + C + c*MAXN;
    const float* cf = ws + OFF_CLSF + c*8;
    const float sv = cf[3], av = cf[4], sqsa = cf[5]*cf[6];
    const float* Gp  = ws + OFF_G  + (size_t)p*T*T;
    const float* g1p = ws + OFF_G1 + p*T;
    const float  ggv = ws[OFF_GG + p];
    const float* Gmp = ws + OFF_GM + (size_t)p*T*C;
    const float gmcv = ws[OFF_GMC + p*C + c];
    const float mmv  = ws[OFF_MM  + p*C + c];

    // ---- build M in rowS layout; pads and rows >= m zeroed ----
    for (int e = tid; e < PACKA; e += NTF){
      int i = row_ofS(e);
      int j = e - rowS(i);
      float v = 0.f;
      if (i < m && j <= i){
        if (i < T){
          v = sv*(Gp[i*T + j] - g1p[i] - g1p[j] + ggv);
          if (j == i) v += 1.0f;
        } else {
          int ua = idxc[i - T];
          if (j < T){
            v = sqsa*(Gp[ua*T + j] - Gmp[j*C + c] - g1p[ua] + gmcv);
          } else {
            int ub = idxc[j - T];
            v = av*(Gp[ua*T + ub] - Gmp[ua*C + c] - Gmp[ub*C + c] + mmv);
            if (j == i) v += 1.0f;
          }
        }
      }
      Lp[e] = v;
    }
    __syncthreads();

    // ---- blocked right-looking Cholesky ----
    for (int k0 = 0; k0 < m; k0 += NB){
      // (a) diag 16x16 Cholesky + inverse inside wave 0 (no barriers)
      if (tid < 64){
        const int lane = tid;
        float a[NB];
        #pragma unroll
        for (int j = 0; j < NB; ++j){
          a[j] = 0.f;
          if (lane < NB && j <= lane) a[j] = Lp[rowS(k0+lane) + k0 + j];
        }
        #pragma unroll
        for (int k = 0; k < NB; ++k){
          float akk = __shfl(a[k], k, 64);
          float inv = rsqrtf(akk);
          a[k] *= inv;
          #pragma unroll
          for (int j = k+1; j < NB; ++j){
            float ljk = __shfl(a[k], j, 64);
            a[j] -= a[k] * ljk;
          }
        }
        float x[NB];
        #pragma unroll
        for (int i = 0; i < NB; ++i){
          float Lii = __shfl(a[i], i, 64);
          float sxx = 0.f;
          #pragma unroll
          for (int k2 = 0; k2 < i; ++k2){
            float Lik = __shfl(a[k2], i, 64);
            sxx += Lik * x[k2];
          }
          float tt = ((i == lane) ? 1.f : 0.f) - sxx;
          x[i] = tt / Lii;
        }
        if (lane < NB){
          #pragma unroll
          for (int i = 0; i < NB; ++i){
            Dv[i][lane] = (i >= lane) ? x[i] : 0.f;
            if (i >= lane) Lp[rowS(k0+i) + k0 + lane] = x[i];
          }
        }
      }
      __syncthreads();

      // (b) panel update: L[r][k0+j] = sum_{kk<=j} A[r][k0+kk] * Dinv[j][kk]
      for (int r = k0 + NB + tid; r < m; r += NTF){
        const int o = rowS(r) + k0;
        float4 A0 = *(const float4*)&Lp[o];
        float4 A1 = *(const float4*)&Lp[o+4];
        float4 A2 = *(const float4*)&Lp[o+8];
        float4 A3 = *(const float4*)&Lp[o+12];
        float ar[NB] = {A0.x,A0.y,A0.z,A0.w, A1.x,A1.y,A1.z,A1.w,
                        A2.x,A2.y,A2.z,A2.w, A3.x,A3.y,A3.z,A3.w};
        float sr[NB];
        #pragma unroll
        for (int j = 0; j < NB; ++j){
          float s = 0.f;
          #pragma unroll
          for (int kk = 0; kk <= j; ++kk) s += ar[kk] * Dv[j][kk];
          sr[j] = s;
        }
        *(float4*)&Lp[o]    = make_float4(sr[0], sr[1], sr[2], sr[3]);
        *(float4*)&Lp[o+4]  = make_float4(sr[4], sr[5], sr[6], sr[7]);
        *(float4*)&Lp[o+8]  = make_float4(sr[8], sr[9], sr[10], sr[11]);
        *(float4*)&Lp[o+12] = make_float4(sr[12], sr[13], sr[14], sr[15]);
      }
      __syncthreads();

      // (c) trailing SYRK directly from Lp (b128 reads; rows >= m are zero)
      const int rs = m - k0 - NB;
      if (rs > 0){
        const int base = k0 + NB;
        const int nt4 = (rs + 3) >> 2;
        const int ntile = (nt4*(nt4+1)) >> 1;
        for (int e2 = tid; e2 < ntile; e2 += NTF){
          const int ti = row_of(e2);
          const int tj = e2 - offr(ti);
          const int gi0 = base + 4*ti, gj0 = base + 4*tj;
          const float* pa0 = &Lp[rowS(gi0)   + k0];
          const float* pa1 = &Lp[rowS(gi0+1) + k0];
          const float* pa2 = &Lp[rowS(gi0+2) + k0];
          const float* pa3 = &Lp[rowS(gi0+3) + k0];
          const float* pb0 = &Lp[rowS(gj0)   + k0];
          const float* pb1 = &Lp[rowS(gj0+1) + k0];
          const float* pb2 = &Lp[rowS(gj0+2) + k0];
          const float* pb3 = &Lp[rowS(gj0+3) + k0];
          float acc[4][4] = {};
          #pragma unroll
          for (int kk = 0; kk < NB; kk += 4){
            float4 a0 = *(const float4*)(pa0+kk);
            float4 a1 = *(const float4*)(pa1+kk);
            float4 a2 = *(const float4*)(pa2+kk);
            float4 a3 = *(const float4*)(pa3+kk);
            float4 b0 = *(const float4*)(pb0+kk);
            float4 b1 = *(const float4*)(pb1+kk);
            float4 b2 = *(const float4*)(pb2+kk);
            float4 b3 = *(const float4*)(pb3+kk);
            acc[0][0] += a0.x*b0.x + a0.y*b0.y + a0.z*b0.z + a0.w*b0.w;
            acc[0][1] += a0.x*b1.x + a0.y*b1.y + a0.z*b1.z + a0.w*b1.w;
            acc[0][2] += a0.x*b2.x + a0.y*b2.y + a0.z*b2.z + a0.w*b2.w;
            acc[0][3] += a0.x*b3.x + a0.y*b3.y + a0.z*b3.z + a0.w*b3.w;
            acc[1][0] += a1.x*b0.x + a1.y*b0.y + a1.z*b0.z + a1.w*b0.w;
            acc[1][1] += a1.x*b1.x + a1.y*b1.y + a1.z*b1.z + a1.w*b1.w;
            acc[1][2] += a1.x*b2.x + a1.y*b2.y + a1.z*b2.z + a1.w*b2.w;
            acc[1][3] += a1.x*b3.x + a1.y*b3.y + a1.z*b3.z + a1.w*b3.w;
            acc[2][0] += a2.x*b0.x + a2.y*b0.y + a2.z*b0.z + a2.w*b0.w;
            acc[2][1] += a2.x*b1.x + a2.y*b1.y + a2.z*b1.z + a2.w*b1.w;
            acc[2][2] += a2.x*b2.x + a2.y*b2.y + a2.z*b2.z + a2.w*b2.w;
            acc[2][3] += a2.x*b3.x + a2.y*b3.y + a2.z*b3.z + a2.w*b3.w;
            acc[3][0] += a3.x*b0.x + a3.y*b0.y + a3.z*b0.z + a3.w*b0.w;
            acc[3][1] += a3.x*b1.x + a3.y*b1.y + a3.z*b1.z + a3.w*b1.w;
            acc[3][2] += a3.x*b2.x + a3.y*b2.y + a3.z*b2.z + a3.w*b2.w;
            acc[3][3] += a3.x*b3.x + a3.y*b3.y + a3.z*b3.z + a3.w*b3.w;
          }
          #pragma unroll
          for (int u2 = 0; u2 < 4; ++u2){
            const int gi = gi0 + u2;
            if (gi < m){
              const int og = rowS(gi);
              if (gj0 + 3 <= gi){
                float4 t = *(float4*)&Lp[og + gj0];
                t.x -= acc[u2][0]; t.y -= acc[u2][1]; t.z -= acc[u2][2]; t.w -= acc[u2][3];
                *(float4*)&Lp[og + gj0] = t;
              } else {
                #pragma unroll
                for (int v = 0; v < 4; ++v){
                  const int gj = gj0 + v;
                  if (gj <= gi) Lp[og + gj] -= acc[u2][v];
                }
              }
            }
          }
        }
      }
      __syncthreads();
    }

    // ---- full triangular inversion in place (ascending block-rows, all b128).
    //      Rounds with i0 >= m skipped — dead rows, never read; W store guards r < m. ----
    for (int I = 1; I < MMAX/NB; ++I){
      const int i0 = I*NB;
      if (i0 >= m) break;
      const int nct = i0 >> 2;
      const int rt = tid & 3, ct = tid >> 2;
      const int rt4 = rt*4;
      const int j0 = ct*4;
      int o0 = 0, o1 = 0, o2 = 0, o3 = 0;
      if (tid < 4*nct){
        const int r0 = i0 + rt4;
        o0 = rowS(r0); o1 = rowS(r0+1); o2 = rowS(r0+2); o3 = rowS(r0+3);
        float acc[4][4] = {};
        for (int k = j0; k < i0; k += 4){
          float4 l0 = *(const float4*)&Lp[o0+k];
          float4 l1 = *(const float4*)&Lp[o1+k];
          float4 l2 = *(const float4*)&Lp[o2+k];
          float4 l3 = *(const float4*)&Lp[o3+k];
          float4 x0 = *(const float4*)&Lp[rowS(k)  +j0];
          float4 x1 = *(const float4*)&Lp[rowS(k+1)+j0];
          float4 x2 = *(const float4*)&Lp[rowS(k+2)+j0];
          float4 x3 = *(const float4*)&Lp[rowS(k+3)+j0];
          acc[0][0] += l0.x*x0.x + l0.y*x1.x + l0.z*x2.x + l0.w*x3.x;
          acc[0][1] += l0.x*x0.y + l0.y*x1.y + l0.z*x2.y + l0.w*x3.y;
          acc[0][2] += l0.x*x0.z + l0.y*x1.z + l0.z*x2.z + l0.w*x3.z;
          acc[0][3] += l0.x*x0.w + l0.y*x1.w + l0.z*x2.w + l0.w*x3.w;
          acc[1][0] += l1.x*x0.x + l1.y*x1.x + l1.z*x2.x + l1.w*x3.x;
          acc[1][1] += l1.x*x0.y + l1.y*x1.y + l1.z*x2.y + l1.w*x3.y;
          acc[1][2] += l1.x*x0.z + l1.y*x1.z + l1.z*x2.z + l1.w*x3.z;
          acc[1][3] += l1.x*x0.w + l1.y*x1.w + l1.z*x2.w + l1.w*x3.w;
          acc[2][0] += l2.x*x0.x + l2.y*x1.x + l2.z*x2.x + l2.w*x3.x;
          acc[2][1] += l2.x*x0.y + l2.y*x1.y + l2.z*x2.y + l2.w*x3.y;
          acc[2][2] += l2.x*x0.z + l2.y*x1.z + l2.z*x2.z + l2.w*x3.z;
          acc[2][3] += l2.x*x0.w + l2.y*x1.w + l2.z*x2.w + l2.w*x3.w;
          acc[3][0] += l3.x*x0.x + l3.y*x1.x + l3.z*x2.x + l3.w*x3.x;
          acc[3][1] += l3.x*x0.y + l3.y*x1.y + l3.z*x2.y + l3.w*x3.y;
          acc[3][2] += l3.x*x0.z + l3.y*x1.z + l3.z*x2.z + l3.w*x3.z;
          acc[3][3] += l3.x*x0.w + l3.y*x1.w + l3.z*x2.w + l3.w*x3.w;
        }
        *(float4*)&Sb[(rt4  )*228 + j0] = make_float4(acc[0][0], acc[0][1], acc[0][2], acc[0][3]);
        *(float4*)&Sb[(rt4+1)*228 + j0] = make_float4(acc[1][0], acc[1][1], acc[1][2], acc[1][3]);
        *(float4*)&Sb[(rt4+2)*228 + j0] = make_float4(acc[2][0], acc[2][1], acc[2][2], acc[2][3]);
        *(float4*)&Sb[(rt4+3)*228 + j0] = make_float4(acc[3][0], acc[3][1], acc[3][2], acc[3][3]);
      }
      __syncthreads();
      if (tid < 4*nct){
        float acc[4][4] = {};
        for (int s = 0; s < rt4 + 4; ++s){
          const float d0 = Lp[o0 + i0 + s];   // pads beyond row give zero
          const float d1 = Lp[o1 + i0 + s];
          const float d2 = Lp[o2 + i0 + s];
          const float d3 = Lp[o3 + i0 + s];
          const float4 sv4 = *(const float4*)&Sb[s*228 + j0];
          acc[0][0] += d0*sv4.x; acc[0][1] += d0*sv4.y; acc[0][2] += d0*sv4.z; acc[0][3] += d0*sv4.w;
          acc[1][0] += d1*sv4.x; acc[1][1] += d1*sv4.y; acc[1][2] += d1*sv4.z; acc[1][3] += d1*sv4.w;
          acc[2][0] += d2*sv4.x; acc[2][1] += d2*sv4.y; acc[2][2] += d2*sv4.z; acc[2][3] += d2*sv4.w;
          acc[3][0] += d3*sv4.x; acc[3][1] += d3*sv4.y; acc[3][2] += d3*sv4.z; acc[3][3] += d3*sv4.w;
        }
        *(float4*)&Lp[o0 + j0] = make_float4(-acc[0][0], -acc[0][1], -acc[0][2], -acc[0][3]);
        *(float4*)&Lp[o1 + j0] = make_float4(-acc[1][0], -acc[1][1], -acc[1][2], -acc[1][3]);
        *(float4*)&Lp[o2 + j0] = make_float4(-acc[2][0], -acc[2][1], -acc[2][2], -acc[2][3]);
        *(float4*)&Lp[o3 + j0] = make_float4(-acc[3][0], -acc[3][1], -acc[3][2], -acc[3][3]);
      }
      __syncthreads();
    }

    // ---- store W = L^-1 as split-f16 planes (hi, lo) in tile-padded rowT layout ----
    _Float16* WH = (_Float16*)(ws + OFF_W) + (size_t)blk * (2*PACKT);
    _Float16* WL = WH + PACKT;
    // R=0: rows 0..63, len 64
    for (int e = tid; e < 64*64; e += NTF){
      int s = e >> 6, j = e & 63, r = s;
      float v = (r < m && j <= r) ? Lp[rowS(r) + j] : 0.f;
      _Float16 h = (_Float16)v;
      WH[e] = h; WL[e] = (_Float16)(v - (float)h);
    }
    // R=1: rows 64..127, len 128
    for (int e = tid; e < 64*128; e += NTF){
      int s = e >> 7, j = e & 127, r = 64 + s;
      float v = (r < m && j <= r) ? Lp[rowS(r) + j] : 0.f;
      _Float16 h = (_Float16)v;
      WH[4096 + e] = h; WL[4096 + e] = (_Float16)(v - (float)h);
    }
    // R=2: rows 128..191, len 192
    for (int e = tid; e < 64*192; e += NTF){
      int x = e >> 6;
      int s = (x*171) >> 9;            // x/3 for x < 512
      int j = e - s*192, r = 128 + s;
      float v = (r < m && j <= r) ? Lp[rowS(r) + j] : 0.f;
      _Float16 h = (_Float16)v;
      WH[12288 + e] = h; WL[12288 + e] = (_Float16)(v - (float)h);
    }
    // R=3: rows 192..255, len 256
    for (int e = tid; e < 64*256; e += NTF){
      int s = e >> 8, j = e & 255, r = 192 + s;
      float v = (r < m && j <= r) ? Lp[rowS(r) + j] : 0.f;
      _Float16 h = (_Float16)v;
      WH[24576 + e] = h; WL[24576 + e] = (_Float16)(v - (float)h);
    }

  } else if (bid < NBLK_FACTOR + NBLK_SQ){
    // ========== sq path: SQ = X Q^T via split-f16 MFMA (64t x 256q tile) ==========
    // SQ = (Xh+Xl)(Qh+Ql) ~= Xh*Qh + Xh*Ql + Xl*Qh, f32 accumulate.
    const int sb = bid - NBLK_FACTOR;
    const int p = sb >> 4, rem = sb & 15;
    const int t0 = (rem >> 2) * 64;        // t-tile base (rows >= T zero-padded)
    const int qb = (rem & 3) * 256;        // q-tile base
    _Float16* XH = u.q.XHs; _Float16* XL = u.q.XLs;
    _Float16* QH = u.q.QHs; _Float16* Qlo = u.q.QLs;
    const float* Xp = X  + (size_t)p*T*F;
    const float* Qp = Qf + (size_t)p*NQ*F;
    const int wv = tid >> 6, ln = tid & 63;
    const int lr = ln & 15, lg = ln >> 4;
    const int wt = (wv & 1) * 32;          // wave t-base within tile
    const int wq = (wv >> 1) * 64;         // wave q-base within tile

    f32x4 acc[2][4] = {};

    for (int kb = 0; kb < F; kb += 64){
      // stage X chunk: 64 rows x 64 k -> f16 hi/lo, stride XQS=72 (bank pad)
      for (int e = tid; e < 64*16; e += NTF){
        const int r = e >> 4, l4 = (e & 15) * 4;
        float4 v = (t0 + r < T) ? *(const float4*)&Xp[(size_t)(t0+r)*F + kb + l4]
                                : make_float4(0.f,0.f,0.f,0.f);
        _Float16 h0=(_Float16)v.x, h1=(_Float16)v.y, h2=(_Float16)v.z, h3=(_Float16)v.w;
        f16x4 hv = {h0,h1,h2,h3};
        f16x4 lv = {(_Float16)(v.x-(float)h0),(_Float16)(v.y-(float)h1),
                    (_Float16)(v.z-(float)h2),(_Float16)(v.w-(float)h3)};
        *(f16x4*)&XH[r*XQS + l4] = hv;
        *(f16x4*)&XL[r*XQS + l4] = lv;
      }
      // stage Q chunk: 256 rows x 64 k
      for (int e = tid; e < 256*16; e += NTF){
        const int r = e >> 4, l4 = (e & 15) * 4;
        float4 v = *(const float4*)&Qp[(size_t)(qb+r)*F + kb + l4];
        _Float16 h0=(_Float16)v.x, h1=(_Float16)v.y, h2=(_Float16)v.z, h3=(_Float16)v.w;
        f16x4 hv = {h0,h1,h2,h3};
        f16x4 lv = {(_Float16)(v.x-(float)h0),(_Float16)(v.y-(float)h1),
                    (_Float16)(v.z-(float)h2),(_Float16)(v.w-(float)h3)};
        *(f16x4*)&QH[r*XQS + l4] = hv;
        *(f16x4*)&Qlo[r*XQS + l4] = lv;
      }
      __syncthreads();
      #pragma unroll
      for (int s = 0; s < 2; ++s){
        const int ko = s*32 + 8*lg;
        f16x8 bh[4], bl[4];
        #pragma unroll
        for (int j = 0; j < 4; ++j){
          const int qr = wq + j*16 + lr;
          bh[j] = *(const f16x8*)&QH[qr*XQS + ko];
          bl[j] = *(const f16x8*)&Qlo[qr*XQS + ko];
        }
        #pragma unroll
        for (int i = 0; i < 2; ++i){
          const int tr = wt + i*16 + lr;
          f16x8 ah = *(const f16x8*)&XH[tr*XQS + ko];
          f16x8 al = *(const f16x8*)&XL[tr*XQS + ko];
          #pragma unroll
          for (int j = 0; j < 4; ++j){
            acc[i][j] = __builtin_amdgcn_mfma_f32_16x16x32_f16(ah, bh[j], acc[i][j], 0, 0, 0);
            acc[i][j] = __builtin_amdgcn_mfma_f32_16x16x32_f16(ah, bl[j], acc[i][j], 0, 0, 0);
            acc[i][j] = __builtin_amdgcn_mfma_f32_16x16x32_f16(al, bh[j], acc[i][j], 0, 0, 0);
          }
        }
      }
      __syncthreads();
    }
    // store: C/D layout col=lane&15, row=(lane>>4)*4+reg
    float* SQp = ws + OFF_SQ + (size_t)p*T*NQ;
    #pragma unroll
    for (int i = 0; i < 2; ++i){
      const int tb = t0 + wt + i*16 + lg*4;
      #pragma unroll
      for (int j = 0; j < 4; ++j){
        const int qc = qb + wq + j*16 + lr;
        #pragma unroll
        for (int r = 0; r < 4; ++r){
          const int t = tb + r;
          if (t < T) SQp[t*NQ + qc] = acc[i][j][r];
        }
      }
    }

  } else if (bid < NBLK_FACTOR + NBLK_SQ + NBLK_MEANS){
    // ================= means path -> output part 2 =================
    const int mb = bid - NBLK_FACTOR - NBLK_SQ;
    const int p = mb / C, c = mb % C;
    const int n = wsI[c];
    const int* idxc = wsI + C + c*MAXN;
    const float nf = ws[OFF_CLSF + c*8];
    const float* Xp = X + (size_t)p*T*F;
    float* o = out + QL + (size_t)(p*C + c)*F;
    for (int f = tid; f < F; f += NTF){
      float s = 0.f;
      for (int j = 0; j < n; ++j) s += Xp[idxc[j]*F + f];
      o[f] = s / nf;
    }

  } else {
    // ================= qnorm path: ||q||^2, 8 rows per wave =================
    const int qb2 = bid - NBLK_FACTOR - NBLK_SQ - NBLK_MEANS;   // [0,128)
    const int w = tid >> 6, lane = tid & 63;
    const int row0 = qb2*64 + w*8;
    for (int i = 0; i < 8; ++i){
      const int row = row0 + i;
      const float4* q4p = (const float4*)(Qf + (size_t)row*F);
      float4 v0 = q4p[lane];
      float4 v1 = q4p[lane + 64];
      float s = v0.x*v0.x + v0.y*v0.y + v0.z*v0.z + v0.w*v0.w
              + v1.x*v1.x + v1.y*v1.y + v1.z*v1.z + v1.w*v1.w;
      for (int off = 32; off; off >>= 1) s += __shfl_down(s, off, 64);
      if (lane == 0) ws[OFF_QN + row] = s;
    }
  }
}

// ---------------- apply: z = W*e via split-f16 MFMA, K-QUARTERED E^T staging
//   (proven R7 version). LDS 27.8 KB -> 5 blocks/CU; accumulators persist
//   across quarters; the next quarter's build-barrier doubles as the
//   Et-overwrite fence. ----------------
__global__ __launch_bounds__(256) void k_apply(float* ws){
  __shared__ __align__(16) _Float16 EtH[64*ETH];  // 9216 B  [q][k-quarter] hi plane
  __shared__ __align__(16) _Float16 EtL[64*ETH];  // 9216 B  [q][k-quarter] lo plane
  __shared__ float Ef[32*65];                     // 8320 B  f32 build chunk [j][q], stride 65
  __shared__ float Part[4][64];                   // 1024 B  per-wave ||z||^2 partials
  const int p = blockIdx.z, c = blockIdx.y, q0 = blockIdx.x*64;
  const int tid = threadIdx.x;
  const int* wsI = (const int*)(ws + OFF_INT);
  const int n = wsI[c], m = T + n;
  const int* idxc = wsI + C + c*MAXN;
  const float* cf = ws + OFF_CLSF + c*8;
  const float sqs = cf[5], sqa = cf[6];
  const float gmcv = ws[OFF_GMC + p*C + c];
  const float mmv  = ws[OFF_MM  + p*C + c];
  const float* Gmp = ws + OFF_GM + (size_t)p*T*C;
  const float* SQp = ws + OFF_SQ + (size_t)p*T*NQ;
  const float* gqp = ws + OFF_GQ + p*NQ + q0;
  const float* qnp = ws + OFF_QN + p*NQ + q0;
  const float* mqp = ws + OFF_MQ + ((size_t)(p*C + c))*NQ + q0;

  const int wv = tid >> 6, ln = tid & 63;
  const int lr = ln & 15;          // A row / B col (q) within tile
  const int lg = ln >> 4;          // k-group
  const _Float16* WH = (const _Float16*)(ws + OFF_W) + (size_t)(p*C + c)*(2*PACKT);
  const _Float16* WL = WH + PACKT;
  int aoff[4];
  #pragma unroll
  for (int i = 0; i < 4; ++i){
    const int t = wv + 4*i;
    aoff[i] = rowT(16*t + lr) + 8*lg;
  }

  f32x4 acc[4][4] = {};            // [rowtile][qtile], 4 f32 each; persists across quarters

  for (int h = 0; h < 4; ++h){
    // ---- build quarter h: E rows [64h, 64h+64) in two 32-row chunks ----
    for (int ch = 0; ch < 2; ++ch){
      const int jbl = ch*32;                // local row base within quarter
      const int jb = h*64 + jbl;            // absolute E row base
      for (int e = tid; e < 32*64; e += 256){
        const int jl = e >> 6, q = e & 63;
        const int j = jb + jl;
        float v = 0.f;
        if (j < T){
          v = sqs*(Gmp[j*C + c] - SQp[j*NQ + q0 + q] - gmcv + gqp[q]);
        } else if (j < m){
          const int u2 = idxc[j - T];
          v = sqa*(Gmp[u2*C + c] - SQp[u2*NQ + q0 + q] - mmv + mqp[q]);
        }
        Ef[jl*65 + q] = v;
      }
      __syncthreads();                      // also fences prior quarter's Et reads
      for (int e = tid; e < 16*64; e += 256){
        const int jp = e & 15, q = e >> 4;
        const int jl = 2*jp;
        const float v0 = Ef[jl*65 + q];
        const float v1 = Ef[(jl+1)*65 + q];
        const _Float16 h0 = (_Float16)v0, h1 = (_Float16)v1;
        f16x2 hv; hv[0] = h0; hv[1] = h1;
        f16x2 lv; lv[0] = (_Float16)(v0 - (float)h0); lv[1] = (_Float16)(v1 - (float)h1);
        *(f16x2*)&EtH[q*ETH + jbl + jl] = hv;
        *(f16x2*)&EtL[q*ETH + jbl + jl] = lv;
      }
      __syncthreads();
    }

    // ---- MFMA over this quarter: s in {2h, 2h+1} ----
    #pragma unroll
    for (int sl = 0; sl < 2; ++sl){
      const int s = 2*h + sl;
      if (2*s > wv + 12) continue;          // no active row-tile for this wave
      const int k0 = 32*s;
      const int bo = lr*ETH + (k0 - 64*h) + 8*lg;
      f16x8 bh[4], bl[4];
      #pragma unroll
      for (int ct2 = 0; ct2 < 4; ++ct2){
        bh[ct2] = *(const f16x8*)&EtH[ct2*16*ETH + bo];
        bl[ct2] = *(const f16x8*)&EtL[ct2*16*ETH + bo];
      }
      #pragma unroll
      for (int i = 0; i < 4; ++i){
        const int t = wv + 4*i;
        if (2*s <= t){                      // triangular K-extent: tile t needs k < 16(t+1)
          f16x8 ah = *(const f16x8*)(WH + aoff[i] + k0);
          f16x8 al = *(const f16x8*)(WL + aoff[i] + k0);
          #pragma unroll
          for (int ct2 = 0; ct2 < 4; ++ct2){
            acc[i][ct2] = __builtin_amdgcn_mfma_f32_16x16x32_f16(ah, bh[ct2], acc[i][ct2], 0, 0, 0);
            acc[i][ct2] = __builtin_amdgcn_mfma_f32_16x16x32_f16(ah, bl[ct2], acc[i][ct2], 0, 0, 0);
            acc[i][ct2] = __builtin_amdgcn_mfma_f32_16x16x32_f16(al, bh[ct2], acc[i][ct2], 0, 0, 0);
          }
        }
      }
    }
  }

  // ---- ||z||^2 per query: per-lane squares, butterfly over k-groups, LDS combine ----
  #pragma unroll
  for (int ct2 = 0; ct2 < 4; ++ct2){
    float sthread = 0.f;
    #pragma unroll
    for (int i = 0; i < 4; ++i){
      const f32x4 a4 = acc[i][ct2];
      sthread += a4[0]*a4[0] + a4[1]*a4[1] + a4[2]*a4[2] + a4[3]*a4[3];
    }
    sthread += __shfl_xor(sthread, 16, 64);
    sthread += __shfl_xor(sthread, 32, 64);
    if (ln < 16) Part[wv][ct2*16 + ln] = sthread;
  }
  __syncthreads();
  if (tid < 64){
    const float tt = Part[0][tid] + Part[1][tid] + Part[2][tid] + Part[3][tid];
    const float quad = mmv - 2.f*mqp[tid] + qnp[tid] - tt;
    ws[OFF_QUAD + ((size_t)p*NQ + q0 + tid)*C + c] = quad;
  }
}

// ---------------- logits: mean over p ----------------
__global__ void k_logits(const float* ws, float* out){
  int lin = blockIdx.x*256 + threadIdx.x;
  if (lin < QL){
    float s = 0.f;
    for (int p = 0; p < P; ++p) s += ws[OFF_QUAD + (size_t)p*NQ*C + lin];
    out[lin] = -s * (1.0f/P);
  }
}

extern "C" void kernel_launch(void* const* d_in, const int* in_sizes, int n_in,
                              void* d_out, int out_size, void* d_ws, size_t ws_size,
                              hipStream_t stream){
  const float* X   = (const float*)d_in[0];
  const int*   lab = (const int*)d_in[1];
  const float* Qf  = (const float*)d_in[2];
  float* out = (float*)d_out;
  float* ws  = (float*)d_ws;

  k_setup   <<<1, 64, 0, stream>>>(lab, ws);
  k_gram    <<<dim3(4,P), 512, 0, stream>>>(X, ws);
  k_pstats_a<<<dim3(25,P), 256, 0, stream>>>(ws);
  k_pstats_b<<<P, 256, 0, stream>>>(ws);
  k_big     <<<NBLK_TOTAL, NTF, 0, stream>>>(X, Qf, ws, out);
  k_qstats  <<<dim3(16,P), 256, 0, stream>>>(ws);
  k_apply   <<<dim3(16,C,P), 256, 0, stream>>>(ws);
  k_logits  <<<QL/256, 256, 0, stream>>>(ws, out);
}